// Round 12
// baseline (58.050 us; speedup 1.0000x reference)
//
#include <hip/hip_runtime.h>
#include <math.h>

#define DD   768
#define BB   32
#define NTP  256        // target pixels per batch (16x16)
#define NSP  1024       // search pixels per batch (32x32)
#define NT   (BB*NTP)   // 8192 target px
#define NS   (BB*NSP)   // 32768 search px
#define ECH  16         // E-chunks for prep (48 rows each)
#define CHE  (DD/ECH)   // 48

// ws layout (floats); float4-aligned offsets
#define OFF_UP  0                      // uPart[ECH][DD]
#define OFF_VP  (OFF_UP + ECH*DD)      // vPart[ECH][DD]
#define OFF_K   (OFF_VP + ECH*DD)      // K1,K2 (+pad)
#define OFF_CNT (OFF_K + 16)           // barrier counter (as uint) +pad
#define OFF_TR0 (OFF_CNT + 16)         // target R dots [NT]
#define OFF_TS0 (OFF_TR0 + NT)         // target S dots [NT]
// total ~ 41K floats ~= 164 KB

#define A5 0.99500999000499900f        // (1 - LR*LAMBDA)^5

// 17 blocks: 16 compute U/V partials over 48-row chunks of w; block 16
// computes K1/K2 and zeroes the barrier counter (every call -> deterministic).
__global__ void k_prep(const float* __restrict__ w, const float* __restrict__ cb,
                       const float* __restrict__ gamma, const float* __restrict__ beta,
                       const float* __restrict__ mean, const float* __restrict__ var,
                       const float* __restrict__ fi, float* __restrict__ ws) {
    int bx = blockIdx.x;
    int t = threadIdx.x;
    if (bx < ECH) {
        __shared__ float wu[CHE], wv[CHE];
        if (t < CHE) {
            int e = bx * CHE + t;
            float inv = gamma[e] / sqrtf(var[e] + 1e-5f);
            wv[t] = inv;
            wu[t] = inv * fi[e];
        }
        __syncthreads();
        if (t < 192) {   // one f4-column (4 d's) per thread
            const float4* w4 = (const float4*)w;
            float4 Ru = {0,0,0,0}, Rv = {0,0,0,0};
            #pragma unroll
            for (int j = 0; j < CHE; ++j) {
                float4 x = w4[(size_t)(bx * CHE + j) * 192 + t];
                float a = wu[j], b = wv[j];
                Ru.x += x.x * a; Ru.y += x.y * a; Ru.z += x.z * a; Ru.w += x.w * a;
                Rv.x += x.x * b; Rv.y += x.y * b; Rv.z += x.z * b; Rv.w += x.w * b;
            }
            *(float4*)(ws + OFF_UP + bx * DD + t * 4) = Ru;
            *(float4*)(ws + OFF_VP + bx * DD + t * 4) = Rv;
        }
    } else {
        if (t == 0) ((unsigned*)ws)[OFF_CNT] = 0u;   // reset barrier each call
        __shared__ float r1[256], r2[256];
        float a1 = 0.f, a2 = 0.f;
        for (int e = t; e < DD; e += 256) {
            float inv = gamma[e] / sqrtf(var[e] + 1e-5f);
            float x = (cb[e] - mean[e]) * inv + beta[e];
            a1 += x * fi[e];
            a2 += x;
        }
        r1[t] = a1; r2[t] = a2;
        __syncthreads();
        for (int s = 128; s > 0; s >>= 1) {
            if (t < s) { r1[t] += r1[t + s]; r2[t] += r2[t + s]; }
            __syncthreads();
        }
        if (t == 0) { ws[OFF_K] = r1[0]; ws[OFF_K + 1] = r2[0]; }
    }
}

// Fused dots + filter + output. 1280 blocks, __launch_bounds__(256,5) ->
// 5 blocks/CU -> all 1280 co-resident (5*256). Deadlock-free regardless:
// waiters (search, ids>=256) wait only on targets (ids 0..255), which are
// dispatched first and never wait.
//   target: 256 = 32 b x 8 px-groups(32px), full 768 ch -> publish dots
//   search: 1024 = 32 b x 32 px-groups(32px), full 768 ch -> dots in LDS,
//           wait, redundant per-batch filter, write final output.
__global__ __launch_bounds__(256, 5) void k_fused(const float* __restrict__ sf,
                                                  const float* __restrict__ tf,
                                                  const float* __restrict__ mask,
                                                  float* __restrict__ ws,
                                                  float* __restrict__ out) {
    int bx = blockIdx.x;
    int t = threadIdx.x;
    int pxf4 = t & 7, sub = t >> 3;       // 8 f4-px, 32 subs (24 ch each)
    bool isT = bx < 256;
    int b, g;
    if (isT) { b = bx >> 3; g = bx & 7; }
    else     { int u = bx - 256; b = u >> 5; g = u & 31; }

    const float4* base;
    int STR;
    if (isT) { base = (const float4*)tf + ((size_t)b * DD + sub * 24) * (NTP/4) + g * 8 + pxf4; STR = NTP/4; }
    else     { base = (const float4*)sf + ((size_t)b * DD + sub * 24) * (NSP/4) + g * 8 + pxf4; STR = NSP/4; }

    // prologue: reduce full U/V from the 16 prep partials (L2-hot)
    __shared__ float su[DD], sv[DD];
    if (t < 192) {
        float4 U = {0,0,0,0}, V = {0,0,0,0};
        #pragma unroll
        for (int ec = 0; ec < ECH; ++ec) {
            float4 a = ((const float4*)(ws + OFF_UP))[ec * 192 + t];
            float4 c = ((const float4*)(ws + OFF_VP))[ec * 192 + t];
            U.x += a.x; U.y += a.y; U.z += a.z; U.w += a.w;
            V.x += c.x; V.y += c.y; V.z += c.z; V.w += c.w;
        }
        ((float4*)su)[t] = U;
        ((float4*)sv)[t] = V;
    }
    __syncthreads();

    // 24 ch/thread, 6-deep rolling prefetch (static indices)
    int chb = sub * 24;
    float4 accR = {0,0,0,0}, accS = {0,0,0,0};
    float4 buf[6];
    #pragma unroll
    for (int k = 0; k < 6; ++k) buf[k] = base[(size_t)k * STR];
    #pragma unroll
    for (int i = 0; i < 24; ++i) {
        float4 v = buf[i % 6];
        if (i < 18) buf[i % 6] = base[(size_t)(i + 6) * STR];
        float u = su[chb + i], vb = sv[chb + i];
        accR.x += v.x * u;  accR.y += v.y * u;  accR.z += v.z * u;  accR.w += v.w * u;
        accS.x += v.x * vb; accS.y += v.y * vb; accS.z += v.z * vb; accS.w += v.w * vb;
    }

    // 32-way LDS reduce over subs
    __shared__ float4 redR[32][8], redS[32][8];
    redR[sub][pxf4] = accR; redS[sub][pxf4] = accS;
    __syncthreads();
    for (int s = 16; s > 0; s >>= 1) {
        if (sub < s) {
            float4 a = redR[sub + s][pxf4], m = redR[sub][pxf4];
            m.x += a.x; m.y += a.y; m.z += a.z; m.w += a.w; redR[sub][pxf4] = m;
            float4 c = redS[sub + s][pxf4], n = redS[sub][pxf4];
            n.x += c.x; n.y += c.y; n.z += c.z; n.w += c.w; redS[sub][pxf4] = n;
        }
        __syncthreads();
    }

    if (isT) {
        // publish target dots, arrive, exit
        if (sub == 0) {
            ((float4*)(ws + OFF_TR0))[b * 64 + g * 8 + pxf4] = redR[0][pxf4];
            ((float4*)(ws + OFF_TS0))[b * 64 + g * 8 + pxf4] = redS[0][pxf4];
        }
        __syncthreads();
        if (t == 0) {
            __threadfence();
            atomicAdd((unsigned*)ws + OFF_CNT, 1u);
        }
        return;
    }

    // search: wait for all 256 target blocks
    if (t == 0) {
        unsigned c;
        do {
            c = __hip_atomic_load((unsigned*)ws + OFF_CNT, __ATOMIC_ACQUIRE,
                                  __HIP_MEMORY_SCOPE_AGENT);
            if (c < 256u) __builtin_amdgcn_s_sleep(16);
        } while (c < 256u);
    }
    __syncthreads();

    // per-batch filter (redundant across this batch's 32 search blocks)
    int p = t, lane = t & 63, wvi = t >> 6;
    int hh = p >> 4, wp = p & 15;
    float K1 = ws[OFF_K], K2 = ws[OFF_K + 1];
    unsigned ru = __hip_atomic_load((const unsigned*)(ws + OFF_TR0) + b * 256 + p,
                                    __ATOMIC_RELAXED, __HIP_MEMORY_SCOPE_AGENT);
    unsigned su_ = __hip_atomic_load((const unsigned*)(ws + OFF_TS0) + b * 256 + p,
                                     __ATOMIC_RELAXED, __HIP_MEMORY_SCOPE_AGENT);
    float r0 = K1 + __uint_as_float(ru);
    float s0 = K2 + __uint_as_float(su_);
    float m = mask[b * 256 + p];
    __shared__ float cross[4];
    auto bsum = [&](float v) -> float {
        #pragma unroll
        for (int o = 32; o > 0; o >>= 1) v += __shfl_xor(v, o, 64);
        if (lane == 0) cross[wvi] = v;
        __syncthreads();
        float r = cross[0] + cross[1] + cross[2] + cross[3];
        __syncthreads();
        return r;
    };
    float msum = bsum(m);
    float sy = bsum(m * (float)hh);
    float sx = bsum(m * (float)wp);
    msum = fmaxf(msum, 1.0f);
    float cy = sy / msum, cx = sx / msum;
    float dx = (float)wp - cx, dy = (float)hh - cy;
    float label = expf(-(dx * dx + dy * dy) * 0.125f);   // 2*sigma^2 = 8
    float A = 1.0f, c = 0.0f;
    const float decay = 1.0f - 0.1f * 0.01f;
    #pragma unroll
    for (int it = 0; it < 5; ++it) {
        float resp = A * r0 + c * s0;
        float gc = (1.0f - resp * label > 0.0f) ? (-label * m) : 0.0f;
        float gsum = bsum(gc) * (1.0f / 256.0f);
        c = decay * c - 0.1f * gsum;
        A *= decay;
    }
    // final combine from this block's own LDS dots
    if (t < 8) {
        float4 R = redR[0][t], S = redS[0][t];
        float4 o;
        o.x = A5 * (K1 + R.x) + c * (K2 + S.x);
        o.y = A5 * (K1 + R.y) + c * (K2 + S.y);
        o.z = A5 * (K1 + R.z) + c * (K2 + S.z);
        o.w = A5 * (K1 + R.w) + c * (K2 + S.w);
        ((float4*)out)[b * 256 + g * 8 + t] = o;
    }
}

extern "C" void kernel_launch(void* const* d_in, const int* in_sizes, int n_in,
                              void* d_out, int out_size, void* d_ws, size_t ws_size,
                              hipStream_t stream) {
    const float* sf    = (const float*)d_in[0];
    const float* tf    = (const float*)d_in[1];
    const float* mask  = (const float*)d_in[2];
    const float* w     = (const float*)d_in[3];
    const float* cb    = (const float*)d_in[4];
    const float* gamma = (const float*)d_in[5];
    const float* beta  = (const float*)d_in[6];
    const float* mean  = (const float*)d_in[7];
    const float* var   = (const float*)d_in[8];
    const float* fi    = (const float*)d_in[9];
    float* out = (float*)d_out;
    float* ws  = (float*)d_ws;

    k_prep <<<ECH + 1, 256, 0, stream>>>(w, cb, gamma, beta, mean, var, fi, ws);
    k_fused<<<1280,    256, 0, stream>>>(sf, tf, mask, ws, out);
}

// Round 13
// 34.810 us; speedup vs baseline: 1.6676x; 1.6676x over previous
//
#include <hip/hip_runtime.h>
#include <math.h>

#define DD   768
#define BB   32
#define NTP  256        // target pixels per batch (16x16)
#define NSP  1024       // search pixels per batch (32x32)
#define NT   (BB*NTP)   // 8192 target px
#define NS   (BB*NSP)   // 32768 search px
#define ECH  16         // E-chunks for prep (48 rows each)
#define CHE  (DD/ECH)   // 48
#define NQ   4          // channel quarters
#define QCH  (DD/NQ)    // 192
#define BUFCH 16        // channels per LDS stage buffer
#define NBUF  (QCH/BUFCH) // 12 buffers per block

// ws layout (floats); float4-aligned offsets
#define OFF_UP  0                      // uPart[ECH][DD]
#define OFF_VP  (OFF_UP + ECH*DD)      // vPart[ECH][DD]
#define OFF_K   (OFF_VP + ECH*DD)      // K1,K2 (+pad)
#define OFF_TR0 (OFF_K + 64)           // target R dots [NQ][NT]
#define OFF_TS0 (OFF_TR0 + NQ*NT)      // target S dots [NQ][NT]
#define OFF_SR  (OFF_TS0 + NQ*NT)      // search R dots [NQ][NS]
#define OFF_SS  (OFF_SR + NQ*NS)       // search S dots [NQ][NS]

#define A5 0.99500999000499900f        // (1 - LR*LAMBDA)^5

typedef __attribute__((address_space(1))) const void glb_cvoid;
typedef __attribute__((address_space(3))) void lds_void;

// 17 blocks: 16 compute U/V partials over 48-row chunks of w; 1 computes K1/K2.
__global__ void k_prep(const float* __restrict__ w, const float* __restrict__ cb,
                       const float* __restrict__ gamma, const float* __restrict__ beta,
                       const float* __restrict__ mean, const float* __restrict__ var,
                       const float* __restrict__ fi, float* __restrict__ ws) {
    int bx = blockIdx.x;
    int t = threadIdx.x;
    if (bx < ECH) {
        __shared__ float wu[CHE], wv[CHE];
        if (t < CHE) {
            int e = bx * CHE + t;
            float inv = gamma[e] / sqrtf(var[e] + 1e-5f);
            wv[t] = inv;
            wu[t] = inv * fi[e];
        }
        __syncthreads();
        if (t < 192) {   // one f4-column (4 d's) per thread
            const float4* w4 = (const float4*)w;
            float4 Ru = {0,0,0,0}, Rv = {0,0,0,0};
            #pragma unroll
            for (int j = 0; j < CHE; ++j) {
                float4 x = w4[(size_t)(bx * CHE + j) * 192 + t];
                float a = wu[j], b = wv[j];
                Ru.x += x.x * a; Ru.y += x.y * a; Ru.z += x.z * a; Ru.w += x.w * a;
                Rv.x += x.x * b; Rv.y += x.y * b; Rv.z += x.z * b; Rv.w += x.w * b;
            }
            *(float4*)(ws + OFF_UP + bx * DD + t * 4) = Ru;
            *(float4*)(ws + OFF_VP + bx * DD + t * 4) = Rv;
        }
    } else {
        __shared__ float r1[256], r2[256];
        float a1 = 0.f, a2 = 0.f;
        for (int e = t; e < DD; e += 256) {
            float inv = gamma[e] / sqrtf(var[e] + 1e-5f);
            float x = (cb[e] - mean[e]) * inv + beta[e];
            a1 += x * fi[e];
            a2 += x;
        }
        r1[t] = a1; r2[t] = a2;
        __syncthreads();
        for (int s = 128; s > 0; s >>= 1) {
            if (t < s) { r1[t] += r1[t + s]; r2[t] += r2[t + s]; }
            __syncthreads();
        }
        if (t == 0) { ws[OFF_K] = r1[0]; ws[OFF_K + 1] = r2[0]; }
    }
}

// 1280 blocks (R7 grid: quarters), async global_load_lds staging.
//   search: 1024 = 32 b x 8 px-groups(128px) x 4 ch-quarters(192ch)
//   target:  256 = 32 b x 2 px-groups(128px) x 4 ch-quarters
// Double-buffered LDS tiles of 16ch x 32f4 (8 KB); 2 global_load_lds (16B)
// per wave per tile -> guaranteed in-flight depth, zero VGPR cost.
__global__ __launch_bounds__(256) void k_big(const float* __restrict__ sf,
                                             const float* __restrict__ tf,
                                             float* __restrict__ ws) {
    int bx = blockIdx.x;
    int t = threadIdx.x;
    int pxf4 = t & 31, sub = t >> 5;      // 32 f4-px, 8 channel-subs
    int wv_ = t >> 6, ln = t & 63;        // wave id, lane

    int b, q, cq; bool isS;
    if (bx < 1024) { isS = true;  cq = bx & 3; q = (bx >> 2) & 7; b = bx >> 5; }
    else           { isS = false; int u = bx - 1024; cq = u & 3; q = (u >> 2) & 1; b = u >> 3; }

    __shared__ float4 stage[2][BUFCH * 32];   // 2 x 8 KB
    __shared__ float su[QCH], sv[QCH];

    // prologue: this block's 192-ch U/V slice from the 16 prep partials (L2-hot)
    if (t < QCH / 4) {                    // 48 threads, one f4 each
        float4 U = {0,0,0,0}, V = {0,0,0,0};
        #pragma unroll
        for (int ec = 0; ec < ECH; ++ec) {
            float4 a = ((const float4*)(ws + OFF_UP))[ec * 192 + cq * 48 + t];
            float4 c = ((const float4*)(ws + OFF_VP))[ec * 192 + cq * 48 + t];
            U.x += a.x; U.y += a.y; U.z += a.z; U.w += a.w;
            V.x += c.x; V.y += c.y; V.z += c.z; V.w += c.w;
        }
        ((float4*)su)[t] = U;
        ((float4*)sv)[t] = V;
    }

    const float4* base;
    int STR;
    float4 *oR, *oS;
    if (isS) {
        base = (const float4*)sf + ((size_t)b * DD + cq * QCH) * (NSP/4) + q * 32;
        STR = NSP / 4;                    // 256
        int g4 = b * 256 + q * 32 + pxf4;
        oR = (float4*)(ws + OFF_SR) + cq * (NS/4) + g4;
        oS = (float4*)(ws + OFF_SS) + cq * (NS/4) + g4;
    } else {
        base = (const float4*)tf + ((size_t)b * DD + cq * QCH) * (NTP/4) + q * 32;
        STR = NTP / 4;                    // 64
        int g4 = b * 64 + q * 32 + pxf4;
        oR = (float4*)(ws + OFF_TR0) + cq * (NT/4) + g4;
        oS = (float4*)(ws + OFF_TS0) + cq * (NT/4) + g4;
    }

    // stage buffer bi with channels [cblk*16, cblk*16+16): 8 instrs, 2/wave.
    auto STAGE = [&](int bi, int cblk) {
        #pragma unroll
        for (int j = 0; j < 2; ++j) {
            int inst = wv_ * 2 + j;             // 0..7
            int f = inst * 64 + ln;             // 0..511
            int ch = f >> 5, p4 = f & 31;       // ch 0..15
            const float4* g = base + (size_t)(cblk * BUFCH + ch) * STR + p4;
            float4* lp = &stage[bi][inst * 64]; // wave-uniform dest
            __builtin_amdgcn_global_load_lds((glb_cvoid*)g, (lds_void*)lp, 16, 0, 0);
        }
    };

    STAGE(0, 0);
    __syncthreads();                      // drains vmcnt -> buffer 0 ready, su/sv ready

    float4 accR = {0,0,0,0}, accS = {0,0,0,0};
    int cur = 0;
    #pragma unroll
    for (int cblk = 0; cblk < NBUF; ++cblk) {
        if (cblk < NBUF - 1) STAGE(cur ^ 1, cblk + 1);
        // consume stage[cur]: 2 ch per thread
        #pragma unroll
        for (int i = 0; i < 2; ++i) {
            int chl = sub * 2 + i;
            float4 v = stage[cur][chl * 32 + pxf4];
            float u = su[cblk * BUFCH + chl], vb = sv[cblk * BUFCH + chl];
            accR.x += v.x * u;  accR.y += v.y * u;  accR.z += v.z * u;  accR.w += v.w * u;
            accS.x += v.x * vb; accS.y += v.y * vb; accS.z += v.z * vb; accS.w += v.w * vb;
        }
        __syncthreads();                  // drains next-tile loads (issued pre-compute)
        cur ^= 1;
    }

    // epilogue: reuse stage buffers as reduction scratch (8x32 f4 each)
    float4* redR = (float4*)&stage[0][0];
    float4* redS = (float4*)&stage[1][0];
    redR[sub * 32 + pxf4] = accR;
    redS[sub * 32 + pxf4] = accS;
    __syncthreads();
    for (int s = 4; s > 0; s >>= 1) {
        if (sub < s) {
            float4 a = redR[(sub + s) * 32 + pxf4], m = redR[sub * 32 + pxf4];
            m.x += a.x; m.y += a.y; m.z += a.z; m.w += a.w; redR[sub * 32 + pxf4] = m;
            float4 c = redS[(sub + s) * 32 + pxf4], n = redS[sub * 32 + pxf4];
            n.x += c.x; n.y += c.y; n.z += c.z; n.w += c.w; redS[sub * 32 + pxf4] = n;
        }
        __syncthreads();
    }
    if (sub == 0) { *oR = redR[pxf4]; *oS = redS[pxf4]; }
}

// Per batch: filter iterations from target dots (sum of 4 quarter partials),
// then final output combine (4 search px per thread).
__global__ void k_final(const float* __restrict__ mask, const float* __restrict__ ws,
                        float* __restrict__ out) {
    int b = blockIdx.x;
    int p = threadIdx.x;
    int lane = p & 63, wv = p >> 6;
    int h = p >> 4, w = p & 15;
    float K1 = ws[OFF_K], K2 = ws[OFF_K + 1];
    float r0 = K1, s0 = K2;
    #pragma unroll
    for (int cq = 0; cq < NQ; ++cq) {
        r0 += ws[OFF_TR0 + cq * NT + b * 256 + p];
        s0 += ws[OFF_TS0 + cq * NT + b * 256 + p];
    }
    float m = mask[b * 256 + p];
    __shared__ float cross[4];
    auto bsum = [&](float v) -> float {
        #pragma unroll
        for (int o = 32; o > 0; o >>= 1) v += __shfl_xor(v, o, 64);
        if (lane == 0) cross[wv] = v;
        __syncthreads();
        float r = cross[0] + cross[1] + cross[2] + cross[3];
        __syncthreads();
        return r;
    };
    float msum = bsum(m);
    float sy = bsum(m * (float)h);
    float sx = bsum(m * (float)w);
    msum = fmaxf(msum, 1.0f);
    float cy = sy / msum, cx = sx / msum;
    float dx = (float)w - cx, dy = (float)h - cy;
    float label = expf(-(dx * dx + dy * dy) * 0.125f);   // 2*sigma^2 = 8
    float A = 1.0f, c = 0.0f;
    const float decay = 1.0f - 0.1f * 0.01f;
    #pragma unroll
    for (int it = 0; it < 5; ++it) {
        float resp = A * r0 + c * s0;
        float gc = (1.0f - resp * label > 0.0f) ? (-label * m) : 0.0f;
        float g = bsum(gc) * (1.0f / 256.0f);
        c = decay * c - 0.1f * g;
        A *= decay;
    }
    // combine: 4 search px per thread
    int g4 = b * 256 + p;                 // f4 index into [NS/4]
    float4 R = {K1, K1, K1, K1}, S = {K2, K2, K2, K2};
    #pragma unroll
    for (int cq = 0; cq < NQ; ++cq) {
        float4 a = ((const float4*)(ws + OFF_SR))[cq * (NS/4) + g4];
        float4 d = ((const float4*)(ws + OFF_SS))[cq * (NS/4) + g4];
        R.x += a.x; R.y += a.y; R.z += a.z; R.w += a.w;
        S.x += d.x; S.y += d.y; S.z += d.z; S.w += d.w;
    }
    float4 o;
    o.x = A5 * R.x + c * S.x;
    o.y = A5 * R.y + c * S.y;
    o.z = A5 * R.z + c * S.z;
    o.w = A5 * R.w + c * S.w;
    ((float4*)out)[g4] = o;
}

extern "C" void kernel_launch(void* const* d_in, const int* in_sizes, int n_in,
                              void* d_out, int out_size, void* d_ws, size_t ws_size,
                              hipStream_t stream) {
    const float* sf    = (const float*)d_in[0];
    const float* tf    = (const float*)d_in[1];
    const float* mask  = (const float*)d_in[2];
    const float* w     = (const float*)d_in[3];
    const float* cb    = (const float*)d_in[4];
    const float* gamma = (const float*)d_in[5];
    const float* beta  = (const float*)d_in[6];
    const float* mean  = (const float*)d_in[7];
    const float* var   = (const float*)d_in[8];
    const float* fi    = (const float*)d_in[9];
    float* out = (float*)d_out;
    float* ws  = (float*)d_ws;

    k_prep <<<ECH + 1, 256, 0, stream>>>(w, cb, gamma, beta, mean, var, fi, ws);
    k_big  <<<1280,    256, 0, stream>>>(sf, tf, ws);
    k_final<<<BB,      256, 0, stream>>>(mask, ws, out);
}

// Round 14
// 34.548 us; speedup vs baseline: 1.6803x; 1.0076x over previous
//
#include <hip/hip_runtime.h>
#include <math.h>

#define DD   768
#define BB   32
#define NTP  256        // target pixels per batch (16x16)
#define NSP  1024       // search pixels per batch (32x32)
#define NT   (BB*NTP)   // 8192 target px
#define NS   (BB*NSP)   // 32768 search px
#define ECH  16         // E-chunks (48 rows each)
#define CHE  (DD/ECH)   // 48
#define NQ   4          // channel quarters
#define QCH  (DD/NQ)    // 192

// ws layout (floats); float4-aligned offsets
#define OFF_UP  0                      // uPart[ECH][DD]
#define OFF_VP  (OFF_UP + ECH*DD)      // vPart[ECH][DD]
#define OFF_K   (OFF_VP + ECH*DD)      // K1,K2 (+pad)
#define OFF_TR0 (OFF_K + 64)           // target R dots [NQ][NT]
#define OFF_TS0 (OFF_TR0 + NQ*NT)      // target S dots [NQ][NT]
#define OFF_SR  (OFF_TS0 + NQ*NT)      // search R dots [NQ][NS]
#define OFF_SS  (OFF_SR + NQ*NS)       // search S dots [NQ][NS]

#define A5 0.99500999000499900f        // (1 - LR*LAMBDA)^5

// 65 blocks: 64 = 16 e-chunks x 4 d-blocks (48 rows x 192 cols each, 12 rows
// per thread + 4-way LDS reduce -> 4x shorter load chain than 17-block version);
// block 64 computes K1/K2.
__global__ void k_prep(const float* __restrict__ w, const float* __restrict__ cb,
                       const float* __restrict__ gamma, const float* __restrict__ beta,
                       const float* __restrict__ mean, const float* __restrict__ var,
                       const float* __restrict__ fi, float* __restrict__ ws) {
    int bx = blockIdx.x;
    int t = threadIdx.x;
    if (bx < 64) {
        int ec = bx >> 2, dq = bx & 3;
        __shared__ float wu[CHE], wv[CHE];
        if (t < CHE) {
            int e = ec * CHE + t;
            float inv = gamma[e] / sqrtf(var[e] + 1e-5f);
            wv[t] = inv;
            wu[t] = inv * fi[e];
        }
        __syncthreads();
        __shared__ float4 pr[4][48], pv[4][48];
        if (t < 192) {
            int tcol = t % 48, trow = t / 48;     // col f4 within d-block, row group
            const float4* w4 = (const float4*)w;
            float4 Ru = {0,0,0,0}, Rv = {0,0,0,0};
            #pragma unroll
            for (int j = 0; j < 12; ++j) {
                int l = trow * 12 + j;            // local row in chunk
                float4 x = w4[(size_t)(ec * CHE + l) * 192 + dq * 48 + tcol];
                float a = wu[l], b = wv[l];
                Ru.x += x.x * a; Ru.y += x.y * a; Ru.z += x.z * a; Ru.w += x.w * a;
                Rv.x += x.x * b; Rv.y += x.y * b; Rv.z += x.z * b; Rv.w += x.w * b;
            }
            pr[trow][tcol] = Ru; pv[trow][tcol] = Rv;
        }
        __syncthreads();
        if (t < 48) {
            float4 U = pr[0][t], V = pv[0][t];
            #pragma unroll
            for (int g = 1; g < 4; ++g) {
                float4 a = pr[g][t], c = pv[g][t];
                U.x += a.x; U.y += a.y; U.z += a.z; U.w += a.w;
                V.x += c.x; V.y += c.y; V.z += c.z; V.w += c.w;
            }
            ((float4*)(ws + OFF_UP + ec * DD))[dq * 48 + t] = U;
            ((float4*)(ws + OFF_VP + ec * DD))[dq * 48 + t] = V;
        }
    } else {
        __shared__ float r1[256], r2[256];
        float a1 = 0.f, a2 = 0.f;
        for (int e = t; e < DD; e += 256) {
            float inv = gamma[e] / sqrtf(var[e] + 1e-5f);
            float x = (cb[e] - mean[e]) * inv + beta[e];
            a1 += x * fi[e];
            a2 += x;
        }
        r1[t] = a1; r2[t] = a2;
        __syncthreads();
        for (int s = 128; s > 0; s >>= 1) {
            if (t < s) { r1[t] += r1[t + s]; r2[t] += r2[t + s]; }
            __syncthreads();
        }
        if (t == 0) { ws[OFF_K] = r1[0]; ws[OFF_K + 1] = r2[0]; }
    }
}

// R7 best-measured k_big (34.6 us total), unchanged.
// 1280 identical blocks = exactly 5/CU.
//   search: 1024 = 32 b x 8 px-groups(128px) x 4 ch-quarters(192ch)
//   target:  256 = 32 b x 2 px-groups(128px) x 4 ch-quarters
// Block = 32 f4-px x 8 subs; 24 ch/thread; 8-deep explicit pipeline.
__global__ __launch_bounds__(256, 5) void k_big(const float* __restrict__ sf,
                                                const float* __restrict__ tf,
                                                float* __restrict__ ws) {
    int bx = blockIdx.x;
    int t = threadIdx.x;
    int pxf4 = t & 31, sub = t >> 5;      // 32 f4-px, 8 channel-subs (24 ch each)

    int b, q, cq; bool isS;
    if (bx < 1024) { isS = true;  cq = bx & 3; q = (bx >> 2) & 7; b = bx >> 5; }
    else           { isS = false; int u = bx - 1024; cq = u & 3; q = (u >> 2) & 1; b = u >> 3; }

    __shared__ float su[QCH], sv[QCH];
    if (t < QCH / 4) {                    // 48 threads, one f4 each
        float4 U = {0,0,0,0}, V = {0,0,0,0};
        #pragma unroll
        for (int ec = 0; ec < ECH; ++ec) {
            float4 a = ((const float4*)(ws + OFF_UP))[ec * 192 + cq * 48 + t];
            float4 c = ((const float4*)(ws + OFF_VP))[ec * 192 + cq * 48 + t];
            U.x += a.x; U.y += a.y; U.z += a.z; U.w += a.w;
            V.x += c.x; V.y += c.y; V.z += c.z; V.w += c.w;
        }
        ((float4*)su)[t] = U;
        ((float4*)sv)[t] = V;
    }
    __syncthreads();

    const float4* base;
    int STR;
    float4 *oR, *oS;
    if (isS) {
        base = (const float4*)sf + ((size_t)b * DD + cq * QCH + sub * 24) * (NSP/4) + q * 32 + pxf4;
        STR = NSP / 4;                    // 256
        int g4 = b * 256 + q * 32 + pxf4;
        oR = (float4*)(ws + OFF_SR) + cq * (NS/4) + g4;
        oS = (float4*)(ws + OFF_SS) + cq * (NS/4) + g4;
    } else {
        base = (const float4*)tf + ((size_t)b * DD + cq * QCH + sub * 24) * (NTP/4) + q * 32 + pxf4;
        STR = NTP / 4;                    // 64
        int g4 = b * 64 + q * 32 + pxf4;
        oR = (float4*)(ws + OFF_TR0) + cq * (NT/4) + g4;
        oS = (float4*)(ws + OFF_TS0) + cq * (NT/4) + g4;
    }

    float4 accR = {0,0,0,0}, accS = {0,0,0,0};
    float4 buf[8];
    #pragma unroll
    for (int k = 0; k < 8; ++k) buf[k] = base[(size_t)k * STR];
    #pragma unroll
    for (int g = 1; g < 3; ++g) {
        float4 nxt[8];
        #pragma unroll
        for (int k = 0; k < 8; ++k) nxt[k] = base[(size_t)(g * 8 + k) * STR];
        #pragma unroll
        for (int k = 0; k < 8; ++k) {
            int ch = sub * 24 + (g - 1) * 8 + k;
            float u = su[ch], v = sv[ch];
            accR.x += buf[k].x * u; accR.y += buf[k].y * u; accR.z += buf[k].z * u; accR.w += buf[k].w * u;
            accS.x += buf[k].x * v; accS.y += buf[k].y * v; accS.z += buf[k].z * v; accS.w += buf[k].w * v;
            buf[k] = nxt[k];
        }
    }
    #pragma unroll
    for (int k = 0; k < 8; ++k) {
        int ch = sub * 24 + 16 + k;
        float u = su[ch], v = sv[ch];
        accR.x += buf[k].x * u; accR.y += buf[k].y * u; accR.z += buf[k].z * u; accR.w += buf[k].w * u;
        accS.x += buf[k].x * v; accS.y += buf[k].y * v; accS.z += buf[k].z * v; accS.w += buf[k].w * v;
    }

    __shared__ float4 redR[8][32], redS[8][32];
    redR[sub][pxf4] = accR; redS[sub][pxf4] = accS;
    __syncthreads();
    for (int s = 4; s > 0; s >>= 1) {
        if (sub < s) {
            float4 a = redR[sub + s][pxf4], m = redR[sub][pxf4];
            m.x += a.x; m.y += a.y; m.z += a.z; m.w += a.w; redR[sub][pxf4] = m;
            float4 c = redS[sub + s][pxf4], n = redS[sub][pxf4];
            n.x += c.x; n.y += c.y; n.z += c.z; n.w += c.w; redS[sub][pxf4] = n;
        }
        __syncthreads();
    }
    if (sub == 0) { *oR = redR[0][pxf4]; *oS = redS[0][pxf4]; }
}

// Per batch: filter iterations from target dots (sum of 4 quarter partials),
// then final output combine (4 search px per thread).
__global__ void k_final(const float* __restrict__ mask, const float* __restrict__ ws,
                        float* __restrict__ out) {
    int b = blockIdx.x;
    int p = threadIdx.x;
    int lane = p & 63, wv = p >> 6;
    int h = p >> 4, w = p & 15;
    float K1 = ws[OFF_K], K2 = ws[OFF_K + 1];
    float r0 = K1, s0 = K2;
    #pragma unroll
    for (int cq = 0; cq < NQ; ++cq) {
        r0 += ws[OFF_TR0 + cq * NT + b * 256 + p];
        s0 += ws[OFF_TS0 + cq * NT + b * 256 + p];
    }
    float m = mask[b * 256 + p];
    __shared__ float cross[4];
    auto bsum = [&](float v) -> float {
        #pragma unroll
        for (int o = 32; o > 0; o >>= 1) v += __shfl_xor(v, o, 64);
        if (lane == 0) cross[wv] = v;
        __syncthreads();
        float r = cross[0] + cross[1] + cross[2] + cross[3];
        __syncthreads();
        return r;
    };
    float msum = bsum(m);
    float sy = bsum(m * (float)h);
    float sx = bsum(m * (float)w);
    msum = fmaxf(msum, 1.0f);
    float cy = sy / msum, cx = sx / msum;
    float dx = (float)w - cx, dy = (float)h - cy;
    float label = expf(-(dx * dx + dy * dy) * 0.125f);   // 2*sigma^2 = 8
    float A = 1.0f, c = 0.0f;
    const float decay = 1.0f - 0.1f * 0.01f;
    #pragma unroll
    for (int it = 0; it < 5; ++it) {
        float resp = A * r0 + c * s0;
        float gc = (1.0f - resp * label > 0.0f) ? (-label * m) : 0.0f;
        float g = bsum(gc) * (1.0f / 256.0f);
        c = decay * c - 0.1f * g;
        A *= decay;
    }
    // combine: 4 search px per thread
    int g4 = b * 256 + p;                 // f4 index into [NS/4]
    float4 R = {K1, K1, K1, K1}, S = {K2, K2, K2, K2};
    #pragma unroll
    for (int cq = 0; cq < NQ; ++cq) {
        float4 a = ((const float4*)(ws + OFF_SR))[cq * (NS/4) + g4];
        float4 d = ((const float4*)(ws + OFF_SS))[cq * (NS/4) + g4];
        R.x += a.x; R.y += a.y; R.z += a.z; R.w += a.w;
        S.x += d.x; S.y += d.y; S.z += d.z; S.w += d.w;
    }
    float4 o;
    o.x = A5 * R.x + c * S.x;
    o.y = A5 * R.y + c * S.y;
    o.z = A5 * R.z + c * S.z;
    o.w = A5 * R.w + c * S.w;
    ((float4*)out)[g4] = o;
}

extern "C" void kernel_launch(void* const* d_in, const int* in_sizes, int n_in,
                              void* d_out, int out_size, void* d_ws, size_t ws_size,
                              hipStream_t stream) {
    const float* sf    = (const float*)d_in[0];
    const float* tf    = (const float*)d_in[1];
    const float* mask  = (const float*)d_in[2];
    const float* w     = (const float*)d_in[3];
    const float* cb    = (const float*)d_in[4];
    const float* gamma = (const float*)d_in[5];
    const float* beta  = (const float*)d_in[6];
    const float* mean  = (const float*)d_in[7];
    const float* var   = (const float*)d_in[8];
    const float* fi    = (const float*)d_in[9];
    float* out = (float*)d_out;
    float* ws  = (float*)d_ws;

    k_prep <<<65,   256, 0, stream>>>(w, cb, gamma, beta, mean, var, fi, ws);
    k_big  <<<1280, 256, 0, stream>>>(sf, tf, ws);
    k_final<<<BB,   256, 0, stream>>>(mask, ws, out);
}